// Round 8
// baseline (477.679 us; speedup 1.0000x reference)
//
#include <hip/hip_runtime.h>
#include <math.h>

#define N_NODES 20000
#define N_EDGES 320000
#define N_GRAPH 64
#define IN_DIM  512
#define HID     256
#define F2      512   // HEADS*HID
#define EPS_BN  1e-5f
#define SLOPE   0.2f
#define SCAN_BLOCKS 79   // ceil(20000/256)
#define N_RT    157      // ceil(20000/128) row tiles
#define RT_PAD  20096    // 157*128: padded Fhi rows so tail A-loads are in-bounds

typedef unsigned short u16;
typedef __attribute__((ext_vector_type(8))) short bf16x8;
typedef __attribute__((ext_vector_type(4))) float floatx4;

// bf16 helpers: storage = upper 16 bits of fp32, round-to-nearest-even
__device__ __forceinline__ u16 bf_hi(float x) {
    unsigned int u = __float_as_uint(x);
    return (u16)((u + 0x7fffu + ((u >> 16) & 1u)) >> 16);
}
__device__ __forceinline__ float bf_val(u16 h) {
    return __uint_as_float((unsigned int)h << 16);
}
__device__ __forceinline__ void unpack2(unsigned int u, float& lo, float& hi) {
    lo = __uint_as_float(u << 16);
    hi = __uint_as_float(u & 0xffff0000u);
}
__device__ __forceinline__ float lr(float x) { return fmaxf(x, SLOPE * x); }

// ---------------- init: zero the ws regions that need it ----------------
__global__ void init_zero_kernel(int* counts, int* cursor, float* stats,
                                 float* h_gnum, float* gden) {
    int i = blockIdx.x * blockDim.x + threadIdx.x;
    if (i < N_NODES) { counts[i] = 0; cursor[i] = 0; }
    if (i < 1024) stats[i] = 0.f;
    if (i < N_GRAPH * HID) h_gnum[i] = 0.f;
    if (i < N_GRAPH) gden[i] = 0.f;
}

// ---------------- feat -> bf16 (row-major preserved, tail rows zeroed) --
__global__ __launch_bounds__(256) void split_feat_kernel(
    const float* __restrict__ X, u16* __restrict__ Hi, int total8, int pad8) {
    int i = blockIdx.x * 256 + threadIdx.x;
    if (i >= pad8) return;
    size_t base = (size_t)i * 8;
    if (i >= total8) {  // zero the pad rows (keeps MFMA tail clean)
        *(uint4*)(Hi + base) = make_uint4(0, 0, 0, 0);
        return;
    }
    float4 x0 = *(const float4*)(X + base);
    float4 x1 = *(const float4*)(X + base + 4);
    float xs[8] = {x0.x, x0.y, x0.z, x0.w, x1.x, x1.y, x1.z, x1.w};
    union { u16 s[8]; uint4 v; } h;
#pragma unroll
    for (int j = 0; j < 8; j++) h.s[j] = bf_hi(xs[j]);
    *(uint4*)(Hi + base) = h.v;
}

// --- transpose + split 4 weights: W[k][n] -> Wt[n][k] hi/lo -------------
// z=0..2: 512x512 (W_src,W_dst,W_skip); z=3: W_red 512x256.
__global__ __launch_bounds__(256) void split_wt_kernel(
    const float* __restrict__ Ws, const float* __restrict__ Wd,
    const float* __restrict__ Wk, const float* __restrict__ Wr,
    u16* __restrict__ Hi, u16* __restrict__ Lo) {
    __shared__ float t[32][33];
    int w = blockIdx.z;
    int ncols = (w == 3) ? 256 : 512;
    int n0 = blockIdx.y * 32;
    if (n0 >= ncols) return;
    const float* W = (w == 0) ? Ws : ((w == 1) ? Wd : ((w == 2) ? Wk : Wr));
    size_t obase = (size_t)w * 512 * 512;
    int k0 = blockIdx.x * 32;
    int tx = threadIdx.x, ty = threadIdx.y;  // 32 x 8
#pragma unroll
    for (int i = 0; i < 4; i++)
        t[ty * 4 + i][tx] = W[(size_t)(k0 + ty * 4 + i) * ncols + n0 + tx];
    __syncthreads();
#pragma unroll
    for (int i = 0; i < 4; i++) {
        float x = t[tx][ty * 4 + i];  // = W[k0+tx][n0+ty*4+i]
        u16 hh = bf_hi(x);
        size_t o = obase + (size_t)(n0 + ty * 4 + i) * 512 + k0 + tx;
        Hi[o] = hh;
        Lo[o] = bf_hi(x - bf_val(hh));
    }
}

// ------- fused triple MFMA GEMM v2: no-LDS, no barriers, XCD-swizzled ---
// {fs,fd,skip} = feat @ {Ws,Wd,Wk}. A fragments loaded directly from
// row-major Fhi (16 rows x 64B contiguous per load — same pattern as B).
// No __syncthreads -> compiler pipelines loads与MFMA with vmcnt(N), never
// a full drain. 1D grid, b&7 = XCD heuristic: all 12 (col,w) blocks of a
// row-tile dispatch consecutively on one XCD -> A row-tile HBM-fetched once.
__global__ __launch_bounds__(256) void gemm_mfma_triple(
    const u16* __restrict__ Fhi, const u16* __restrict__ Wthi,
    const float* __restrict__ b_src, const float* __restrict__ b_dst,
    const float* __restrict__ b_skip,
    u16* __restrict__ FS16, u16* __restrict__ FD16, float* __restrict__ h1) {
    int b = blockIdx.x;
    int xcd = b & 7, slot = b >> 3;
    int rt = (slot / 12) * 8 + xcd;
    if (rt >= N_RT) return;
    int cw = slot % 12;
    int w_idx = cw >> 2;
    int col0 = (cw & 3) * 128;
    int row0 = rt * 128;
    int tid = threadIdx.x;
    int lane = tid & 63, wave = tid >> 6;
    int wm = (wave & 1) * 64, wn = (wave >> 1) * 64;
    int quad = lane >> 4, l16 = lane & 15;

    const u16* Wb = Wthi + (size_t)w_idx * 512 * 512;
    // per-lane base pointers (k advances by +32 elements = +64B)
    const u16* aP[4];
    const u16* bP[4];
#pragma unroll
    for (int mt = 0; mt < 4; mt++)
        aP[mt] = Fhi + (size_t)(row0 + wm + mt * 16 + l16) * 512 + quad * 8;
#pragma unroll
    for (int nt = 0; nt < 4; nt++)
        bP[nt] = Wb + (size_t)(col0 + wn + nt * 16 + l16) * 512 + quad * 8;

    floatx4 acc[4][4];
#pragma unroll
    for (int i = 0; i < 4; i++)
#pragma unroll
        for (int j = 0; j < 4; j++) acc[i][j] = (floatx4){0.f, 0.f, 0.f, 0.f};

#pragma unroll 2
    for (int k0 = 0; k0 < 512; k0 += 32) {
        union { uint4 u; bf16x8 v; } a[4], bb[4];
#pragma unroll
        for (int mt = 0; mt < 4; mt++) a[mt].u = *(const uint4*)(aP[mt] + k0);
#pragma unroll
        for (int nt = 0; nt < 4; nt++) bb[nt].u = *(const uint4*)(bP[nt] + k0);
#pragma unroll
        for (int mt = 0; mt < 4; mt++)
#pragma unroll
            for (int nt = 0; nt < 4; nt++)
                acc[mt][nt] = __builtin_amdgcn_mfma_f32_16x16x32_bf16(a[mt].v, bb[nt].v, acc[mt][nt], 0, 0, 0);
    }

    const float* bias = (w_idx == 0) ? b_src : ((w_idx == 1) ? b_dst : b_skip);
    float bv[4];
#pragma unroll
    for (int nt = 0; nt < 4; nt++) bv[nt] = bias[col0 + wn + nt * 16 + l16];
#pragma unroll
    for (int mt = 0; mt < 4; mt++) {
#pragma unroll
        for (int r = 0; r < 4; r++) {
            int m = row0 + wm + mt * 16 + quad * 4 + r;
            if (m < N_NODES) {
#pragma unroll
                for (int nt = 0; nt < 4; nt++) {
                    int n = col0 + wn + nt * 16 + l16;
                    float vv = acc[mt][nt][r] + bv[nt];
                    if (w_idx == 0)      FS16[(size_t)m * 512 + n] = bf_hi(vv);
                    else if (w_idx == 1) FD16[(size_t)m * 512 + n] = bf_hi(vv);
                    else                 h1[(size_t)m * 512 + n] = vv;
                }
            }
        }
    }
}

// ------------------- MFMA GEMM (reducer): 3-term + BN fold --------------
__global__ __launch_bounds__(256) void gemm_mfma_red(
    const float* __restrict__ Af,
    const u16* __restrict__ Bhi, const u16* __restrict__ Blo,
    const float* __restrict__ bias, float* __restrict__ C,
    int Nrows, int M,
    const float* __restrict__ bscale, const float* __restrict__ bshift) {
    __shared__ u16 AsHi[128 * 40];
    __shared__ u16 AsLo[128 * 40];
    __shared__ float sBN[1024];
    int tid = threadIdx.x;
    int row0 = blockIdx.x * 128;
    int col0 = blockIdx.y * 128;
    int lane = tid & 63, wave = tid >> 6;
    int wm = (wave & 1) * 64, wn = (wave >> 1) * 64;
    int quad = lane >> 4, l16 = lane & 15;

    sBN[tid] = bscale[tid]; sBN[256 + tid] = bscale[256 + tid];
    sBN[512 + tid] = bshift[tid]; sBN[768 + tid] = bshift[256 + tid];
    __syncthreads();

    int sr = tid >> 1, sh = (tid & 1) * 16;
    int grow = row0 + sr;
    bool ok = grow < Nrows;
    u16* sA_hi = &AsHi[sr * 40 + sh];
    u16* sA_lo = &AsLo[sr * 40 + sh];

    floatx4 acc[4][4];
#pragma unroll
    for (int i = 0; i < 4; i++)
#pragma unroll
        for (int j = 0; j < 4; j++) acc[i][j] = (floatx4){0.f, 0.f, 0.f, 0.f};

    for (int k0 = 0; k0 < 512; k0 += 32) {
        float v[16];
        if (ok) {
            const float* g = Af + (size_t)grow * 512 + k0 + sh;
            *(float4*)&v[0]  = *(const float4*)(g);
            *(float4*)&v[4]  = *(const float4*)(g + 4);
            *(float4*)&v[8]  = *(const float4*)(g + 8);
            *(float4*)&v[12] = *(const float4*)(g + 12);
        } else {
#pragma unroll
            for (int j = 0; j < 16; j++) v[j] = 0.f;
        }
        union { u16 s[8]; uint4 u; } h0_, h1_, l0_, l1_;
#pragma unroll
        for (int j = 0; j < 16; j++) {
            int kc = k0 + sh + j;
            float x = v[j] * sBN[kc] + sBN[512 + kc];
            u16 hh = bf_hi(x);
            u16 ll = bf_hi(x - bf_val(hh));
            if (j < 8) { h0_.s[j] = hh; l0_.s[j] = ll; }
            else       { h1_.s[j - 8] = hh; l1_.s[j - 8] = ll; }
        }
        union { uint4 u; bf16x8 v; } bh[4], bl[4];
#pragma unroll
        for (int nt = 0; nt < 4; nt++) {
            size_t off = (size_t)(col0 + wn + nt * 16 + l16) * 512 + k0 + quad * 8;
            bh[nt].u = *(const uint4*)(Bhi + off);
            bl[nt].u = *(const uint4*)(Blo + off);
        }
        __syncthreads();
        *(uint4*)(sA_hi + 0) = h0_.u;
        *(uint4*)(sA_hi + 8) = h1_.u;
        *(uint4*)(sA_lo + 0) = l0_.u;
        *(uint4*)(sA_lo + 8) = l1_.u;
        __syncthreads();
#pragma unroll
        for (int mt = 0; mt < 4; mt++) {
            int me = (wm + mt * 16 + l16) * 40 + quad * 8;
            bf16x8 ah = *(const bf16x8*)&AsHi[me];
            bf16x8 al = *(const bf16x8*)&AsLo[me];
#pragma unroll
            for (int nt = 0; nt < 4; nt++) {
                acc[mt][nt] = __builtin_amdgcn_mfma_f32_16x16x32_bf16(ah, bh[nt].v, acc[mt][nt], 0, 0, 0);
                acc[mt][nt] = __builtin_amdgcn_mfma_f32_16x16x32_bf16(ah, bl[nt].v, acc[mt][nt], 0, 0, 0);
                acc[mt][nt] = __builtin_amdgcn_mfma_f32_16x16x32_bf16(al, bh[nt].v, acc[mt][nt], 0, 0, 0);
            }
        }
    }

    float bv[4];
#pragma unroll
    for (int nt = 0; nt < 4; nt++) bv[nt] = bias[col0 + wn + nt * 16 + l16];
#pragma unroll
    for (int mt = 0; mt < 4; mt++) {
#pragma unroll
        for (int r = 0; r < 4; r++) {
            int m = row0 + wm + mt * 16 + quad * 4 + r;
            if (m < Nrows) {
#pragma unroll
                for (int nt = 0; nt < 4; nt++) {
                    int n = col0 + wn + nt * 16 + l16;
                    C[(size_t)m * M + n] = acc[mt][nt][r] + bv[nt];
                }
            }
        }
    }
}

// ---------------- CSR build ----------------
__global__ void hist_kernel(const int* __restrict__ dst, int* __restrict__ counts) {
    int e = blockIdx.x * blockDim.x + threadIdx.x;
    if (e < N_EDGES) atomicAdd(&counts[dst[e]], 1);
}

__global__ __launch_bounds__(256) void scan_local_kernel(
    const int* __restrict__ counts, int* __restrict__ row_ptr, int* __restrict__ bsum) {
    __shared__ int buf[256];
    int b = blockIdx.x, tid = threadIdx.x;
    int i = b * 256 + tid;
    buf[tid] = (i < N_NODES) ? counts[i] : 0;
    __syncthreads();
    for (int off = 1; off < 256; off <<= 1) {
        int t = (tid >= off) ? buf[tid - off] : 0;
        __syncthreads();
        buf[tid] += t;
        __syncthreads();
    }
    if (i < N_NODES) row_ptr[i + 1] = buf[tid];
    if (tid == 255) bsum[b] = buf[255];
}

__global__ __launch_bounds__(256) void scan_fixup_kernel(
    const int* __restrict__ bsum, int* __restrict__ row_ptr) {
    __shared__ int red[256];
    int b = blockIdx.x, tid = threadIdx.x;
    red[tid] = (tid < b) ? bsum[tid] : 0;
    __syncthreads();
    for (int off = 128; off > 0; off >>= 1) {
        if (tid < off) red[tid] += red[tid + off];
        __syncthreads();
    }
    int offset = red[0];
    int i = b * 256 + tid;
    if (i < N_NODES) row_ptr[i + 1] += offset;
    if (b == 0 && tid == 0) row_ptr[0] = 0;
}

__global__ void scatter_kernel(const int* __restrict__ src, const int* __restrict__ dst,
                               const int* __restrict__ row_ptr,
                               int* __restrict__ cursor, int* __restrict__ csr_src) {
    int e = blockIdx.x * blockDim.x + threadIdx.x;
    if (e < N_EDGES) {
        int d = dst[e];
        int pos = atomicAdd(&cursor[d], 1);
        csr_src[row_ptr[d] + pos] = src[e];
    }
}

// -------- fused edge phase v4: SINGLE PASS ------------------------------
__global__ __launch_bounds__(256) void edge_fused_kernel(
    const u16* __restrict__ FS16, const u16* __restrict__ FD16,
    const float* __restrict__ attn, const int* __restrict__ csr_src,
    const int* __restrict__ row_ptr, float* __restrict__ h1) {
    __shared__ float red[3 * 512];
    __shared__ float den[2];
    int n = blockIdx.x, tid = threadIdx.x;
    int lane = tid & 63, wave = tid >> 6;
    int beg = row_ptr[n], end = row_ptr[n + 1], deg = end - beg;
    if (tid < 2) den[tid] = 0.f;

    float fdv[8], aw[8];
    {
        uint4 q = *(const uint4*)(FD16 + (size_t)n * 512 + 8 * lane);
        unpack2(q.x, fdv[0], fdv[1]); unpack2(q.y, fdv[2], fdv[3]);
        unpack2(q.z, fdv[4], fdv[5]); unpack2(q.w, fdv[6], fdv[7]);
        float4 a0 = *(const float4*)(attn + 8 * lane);
        float4 a1 = *(const float4*)(attn + 8 * lane + 4);
        aw[0] = a0.x; aw[1] = a0.y; aw[2] = a0.z; aw[3] = a0.w;
        aw[4] = a1.x; aw[5] = a1.y; aw[6] = a1.z; aw[7] = a1.w;
    }
    __syncthreads();  // den init visible before LDS atomics

    float acc[8] = {0.f, 0.f, 0.f, 0.f, 0.f, 0.f, 0.f, 0.f};
    float dp = 0.f;
    for (int j = wave; j < deg; j += 4) {
        int s = csr_src[beg + j];
        uint4 q = *(const uint4*)(FS16 + (size_t)s * 512 + 8 * lane);
        float f[8];
        unpack2(q.x, f[0], f[1]); unpack2(q.y, f[2], f[3]);
        unpack2(q.z, f[4], f[5]); unpack2(q.w, f[6], f[7]);
        float p = 0.f;
#pragma unroll
        for (int k = 0; k < 8; k++) p += lr(f[k] + fdv[k]) * aw[k];
#pragma unroll
        for (int off = 16; off > 0; off >>= 1) p += __shfl_xor(p, off, 64);
        float ex = expf(p);  // shift-invariant: no max pass needed
#pragma unroll
        for (int k = 0; k < 8; k++) acc[k] += ex * f[k];
        if ((lane & 31) == 0) dp += ex;
    }
    if ((lane & 31) == 0) atomicAdd(&den[lane >> 5], dp);

    if (wave > 0) {
        float* r = &red[(wave - 1) * 512 + lane * 8];
        *(float4*)(r + 0) = *(float4*)&acc[0];
        *(float4*)(r + 4) = *(float4*)&acc[4];
    }
    __syncthreads();
    if (wave == 0) {
#pragma unroll
        for (int w = 0; w < 3; w++) {
            const float* r = &red[w * 512 + lane * 8];
#pragma unroll
            for (int k = 0; k < 8; k++) acc[k] += r[k];
        }
        float d = (lane < 32) ? den[0] : den[1];
        float inv = d > 0.f ? 1.f / d : 0.f;
        float* hp = h1 + (size_t)n * 512 + 8 * lane;
        float4 s0 = *(float4*)(hp);
        float4 s1 = *(float4*)(hp + 4);
        float v[8];
#pragma unroll
        for (int k = 0; k < 8; k++) {
            float x = acc[k] * inv;
            v[k] = x > 0.f ? x : expm1f(x);
        }
        s0.x += v[0]; s0.y += v[1]; s0.z += v[2]; s0.w += v[3];
        s1.x += v[4]; s1.y += v[5]; s1.z += v[6]; s1.w += v[7];
        *(float4*)(hp) = s0;
        *(float4*)(hp + 4) = s1;
    }
}

// ---------------- BatchNorm stats ----------------
__global__ __launch_bounds__(256) void bn_stats_kernel(const float* __restrict__ h1,
                                                       float* __restrict__ stats,
                                                       int rows_per_block) {
    int tid = threadIdx.x;
    int r0 = blockIdx.x * rows_per_block;
    int r1 = min(r0 + rows_per_block, N_NODES);
    float s0 = 0.f, q0 = 0.f, s1 = 0.f, q1 = 0.f;
    for (int r = r0; r < r1; r++) {
        float a = h1[(size_t)r * F2 + tid];
        float b = h1[(size_t)r * F2 + 256 + tid];
        s0 += a; q0 += a * a;
        s1 += b; q1 += b * b;
    }
    atomicAdd(&stats[tid], s0);
    atomicAdd(&stats[256 + tid], s1);
    atomicAdd(&stats[512 + tid], q0);
    atomicAdd(&stats[512 + 256 + tid], q1);
}

__global__ void bn_finalize_kernel(const float* __restrict__ stats,
                                   const float* __restrict__ gamma,
                                   const float* __restrict__ beta,
                                   float* __restrict__ bscale, float* __restrict__ bshift) {
    int c = threadIdx.x;  // 512 threads
    float mu = stats[c] / (float)N_NODES;
    float var = stats[512 + c] / (float)N_NODES - mu * mu;
    float sc = gamma[c] * rsqrtf(var + EPS_BN);
    bscale[c] = sc;
    bshift[c] = beta[c] - mu * sc;
}

// ---------------- gate scores (b_gate dropped: softmax shift-invariant) -
__global__ __launch_bounds__(256) void gate_kernel(const float* __restrict__ hr,
                                                   const float* __restrict__ wg,
                                                   float* __restrict__ gate) {
    int n = blockIdx.x * 4 + (threadIdx.x >> 6);
    int lane = threadIdx.x & 63;
    const float4* row = (const float4*)(hr + (size_t)n * HID);
    const float4* w = (const float4*)wg;
    float4 a = row[lane], b = w[lane];
    float p = a.x * b.x + a.y * b.y + a.z * b.z + a.w * b.w;
#pragma unroll
    for (int off = 32; off > 0; off >>= 1) p += __shfl_down(p, off, 64);
    if (lane == 0) gate[n] = p;
}

// ---------------- per-graph attention pooling: 8 partial blocks / graph -
__device__ __forceinline__ int lower_bound_dev(const int* a, int n, int v) {
    int lo = 0, hi = n;
    while (lo < hi) {
        int mid = (lo + hi) >> 1;
        if (a[mid] < v) lo = mid + 1; else hi = mid;
    }
    return lo;
}

__global__ __launch_bounds__(256) void pool_partial_kernel(
    const float* __restrict__ hr, const float* __restrict__ gate,
    const int* __restrict__ gids, float* __restrict__ h_gnum,
    float* __restrict__ gden) {
    int b = blockIdx.x;
    int g = b >> 3, part = b & 7;
    int tid = threadIdx.x;
    int start = lower_bound_dev(gids, N_NODES, g);
    int end = lower_bound_dev(gids, N_NODES, g + 1);
    int span = end - start;
    int p_beg = start + (span * part) / 8;
    int p_end = start + (span * (part + 1)) / 8;
    if (p_beg >= p_end) return;
    __shared__ float wa[256];
    __shared__ float red[256];
    float acc = 0.f, denacc = 0.f;
    for (int cbeg = p_beg; cbeg < p_end; cbeg += 256) {
        int c = min(256, p_end - cbeg);
        float e = 0.f;
        if (tid < c) { e = expf(gate[cbeg + tid]); wa[tid] = e; }  // |gate| << 1: safe
        red[tid] = (tid < c) ? e : 0.f;
        __syncthreads();
        for (int off = 128; off > 0; off >>= 1) {
            if (tid < off) red[tid] += red[tid + off];
            __syncthreads();
        }
        denacc += red[0];
        for (int i = 0; i < c; i++) acc += wa[i] * hr[(size_t)(cbeg + i) * HID + tid];
        __syncthreads();
    }
    atomicAdd(&h_gnum[g * HID + tid], acc);
    if (tid == 0) atomicAdd(&gden[g], denacc);
}

// ---------------- classifier (finalizes pooling divide) -----------------
__global__ __launch_bounds__(128) void classifier_kernel(
    const float* __restrict__ h_gnum, const float* __restrict__ gden,
    const float* __restrict__ W1, const float* __restrict__ b1,
    const float* __restrict__ W2, const float* __restrict__ b2,
    float* __restrict__ out) {
    int g = blockIdx.x;
    int tid = threadIdx.x;  // 128
    __shared__ float hg[256];
    __shared__ float z1[128];
    float d = gden[g];
    float invd = d > 0.f ? 1.f / d : 0.f;
    hg[tid] = h_gnum[g * HID + tid] * invd;
    hg[tid + 128] = h_gnum[g * HID + tid + 128] * invd;
    __syncthreads();
    float a = b1[tid];
#pragma unroll 8
    for (int k = 0; k < 256; k++) a += hg[k] * W1[k * 128 + tid];
    z1[tid] = a > 0.f ? a : 0.f;
    __syncthreads();
    if (tid < 10) {
        float o = b2[tid];
#pragma unroll 8
        for (int j = 0; j < 128; j++) o += z1[j] * W2[j * 10 + tid];
        out[g * 10 + tid] = o;
    }
}

// ---------------- launcher ----------------
extern "C" void kernel_launch(void* const* d_in, const int* in_sizes, int n_in,
                              void* d_out, int out_size, void* d_ws, size_t ws_size,
                              hipStream_t stream) {
    const float* feat   = (const float*)d_in[0];
    const int*   src    = (const int*)d_in[1];
    const int*   dst    = (const int*)d_in[2];
    const int*   gids   = (const int*)d_in[3];
    const float* W_src  = (const float*)d_in[4];
    const float* b_src  = (const float*)d_in[5];
    const float* W_dst  = (const float*)d_in[6];
    const float* b_dst  = (const float*)d_in[7];
    const float* attn   = (const float*)d_in[8];
    const float* W_skip = (const float*)d_in[9];
    const float* b_skip = (const float*)d_in[10];
    const float* gamma  = (const float*)d_in[11];
    const float* beta   = (const float*)d_in[12];
    const float* W_red  = (const float*)d_in[13];
    const float* b_red  = (const float*)d_in[14];
    const float* w_gate = (const float*)d_in[15];
    const float* W1     = (const float*)d_in[17];
    const float* b1     = (const float*)d_in[18];
    const float* W2     = (const float*)d_in[19];
    const float* b2     = (const float*)d_in[20];
    float* out = (float*)d_out;

    char* p = (char*)d_ws;
    auto alloc = [&](size_t bytes) -> char* {
        char* r = p;
        p += (bytes + 255) & ~(size_t)255;
        return r;
    };
    u16*   FS16     = (u16*)alloc((size_t)N_NODES * F2 * 2);
    u16*   FD16     = (u16*)alloc((size_t)N_NODES * F2 * 2);
    float* h1       = (float*)alloc((size_t)N_NODES * F2 * 4);
    float* gate     = (float*)alloc((size_t)N_NODES * 4);
    float* stats    = (float*)alloc(1024 * 4);
    float* bn_scale = (float*)alloc(512 * 4);
    float* bn_shift = (float*)alloc(512 * 4);
    float* h_gnum   = (float*)alloc((size_t)N_GRAPH * HID * 4);
    float* gden     = (float*)alloc((size_t)N_GRAPH * 4);
    int* counts     = (int*)alloc((size_t)N_NODES * 4);
    int* row_ptr    = (int*)alloc((size_t)(N_NODES + 1) * 4);
    int* cursor     = (int*)alloc((size_t)N_NODES * 4);
    int* csr_src    = (int*)alloc((size_t)N_EDGES * 4);
    int* bsum       = (int*)alloc((size_t)SCAN_BLOCKS * 4);
    u16* Fhi        = (u16*)alloc((size_t)RT_PAD * IN_DIM * 2);  // padded; aliased as hr later
    u16* Wthi       = (u16*)alloc((size_t)4 * 512 * 512 * 2);
    u16* Wtlo       = (u16*)alloc((size_t)4 * 512 * 512 * 2);
    // hr (20.48 MB) aliases Fhi (20.58 MB): Fhi's last use (input GEMMs)
    // strictly precedes hr's first write (reducer GEMM).
    float* hr = (float*)Fhi;
    (void)ws_size; (void)in_sizes; (void)n_in; (void)out_size;

    const size_t WSZ = (size_t)512 * 512;

    // 1. init + input conversions
    init_zero_kernel<<<(N_NODES + 255) / 256, 256, 0, stream>>>(counts, cursor, stats, h_gnum, gden);
    split_feat_kernel<<<(RT_PAD * IN_DIM / 8 + 255) / 256, 256, 0, stream>>>(
        feat, Fhi, N_NODES * IN_DIM / 8, RT_PAD * IN_DIM / 8);
    split_wt_kernel<<<dim3(16, 16, 4), dim3(32, 8), 0, stream>>>(
        W_src, W_dst, W_skip, W_red, Wthi, Wtlo);

    // 2. fused input GEMM triple v2 (no-LDS, XCD-swizzled, 1920 blocks)
    gemm_mfma_triple<<<dim3(((N_RT + 7) / 8) * 8 * 12), 256, 0, stream>>>(
        Fhi, Wthi, b_src, b_dst, b_skip, FS16, FD16, h1);

    // 3-5. CSR by dst
    hist_kernel<<<(N_EDGES + 255) / 256, 256, 0, stream>>>(dst, counts);
    scan_local_kernel<<<SCAN_BLOCKS, 256, 0, stream>>>(counts, row_ptr, bsum);
    scan_fixup_kernel<<<SCAN_BLOCKS, 256, 0, stream>>>(bsum, row_ptr);
    scatter_kernel<<<(N_EDGES + 255) / 256, 256, 0, stream>>>(src, dst, row_ptr, cursor, csr_src);

    // 6. fused edge phase v4 (single pass)
    edge_fused_kernel<<<N_NODES, 256, 0, stream>>>(FS16, FD16, attn, csr_src, row_ptr, h1);

    // 7-8. BatchNorm stats -> scale/shift
    bn_stats_kernel<<<500, 256, 0, stream>>>(h1, stats, 40);
    bn_finalize_kernel<<<1, 512, 0, stream>>>(stats, gamma, beta, bn_scale, bn_shift);

    // 9. hr = BN(h1) @ W_red + b_red  (MFMA, 3-term, BN fold at staging)
    dim3 g256((N_NODES + 127) / 128, 2);
    gemm_mfma_red<<<g256, 256, 0, stream>>>(
        h1, Wthi + 3 * WSZ, Wtlo + 3 * WSZ, b_red, hr, N_NODES, HID,
        bn_scale, bn_shift);

    // 10. gate
    gate_kernel<<<N_NODES / 4, 256, 0, stream>>>(hr, w_gate, gate);

    // 11. per-graph pooling (8 partial blocks per graph)
    pool_partial_kernel<<<N_GRAPH * 8, 256, 0, stream>>>(hr, gate, gids, h_gnum, gden);

    // 12. classifier (+ pooling divide)
    classifier_kernel<<<N_GRAPH, 128, 0, stream>>>(h_gnum, gden, W1, b1, W2, b2, out);
}

// Round 9
// 433.499 us; speedup vs baseline: 1.1019x; 1.1019x over previous
//
#include <hip/hip_runtime.h>
#include <math.h>

#define N_NODES 20000
#define N_EDGES 320000
#define N_GRAPH 64
#define IN_DIM  512
#define HID     256
#define F2      512   // HEADS*HID
#define EPS_BN  1e-5f
#define SLOPE   0.2f
#define SCAN_BLOCKS 79   // ceil(20000/256)
#define N_RT    157      // ceil(20000/128) row tiles
#define RT_PAD  20096    // 157*128: padded Fhi rows so tail A-loads are in-bounds

typedef unsigned short u16;
typedef __attribute__((ext_vector_type(8))) short bf16x8;
typedef __attribute__((ext_vector_type(4))) float floatx4;

// bf16 helpers: storage = upper 16 bits of fp32, round-to-nearest-even
__device__ __forceinline__ u16 bf_hi(float x) {
    unsigned int u = __float_as_uint(x);
    return (u16)((u + 0x7fffu + ((u >> 16) & 1u)) >> 16);
}
__device__ __forceinline__ float bf_val(u16 h) {
    return __uint_as_float((unsigned int)h << 16);
}
__device__ __forceinline__ void unpack2(unsigned int u, float& lo, float& hi) {
    lo = __uint_as_float(u << 16);
    hi = __uint_as_float(u & 0xffff0000u);
}
__device__ __forceinline__ float lr(float x) { return fmaxf(x, SLOPE * x); }

// ---------------- init: zero the ws regions that need it ----------------
__global__ void init_zero_kernel(int* counts, int* cursor, float* stats,
                                 float* h_gnum, float* gden) {
    int i = blockIdx.x * blockDim.x + threadIdx.x;
    if (i < N_NODES) { counts[i] = 0; cursor[i] = 0; }
    if (i < 1024) stats[i] = 0.f;
    if (i < N_GRAPH * HID) h_gnum[i] = 0.f;
    if (i < N_GRAPH) gden[i] = 0.f;
}

// ---------------- feat -> bf16 (row-major preserved, tail rows zeroed) --
__global__ __launch_bounds__(256) void split_feat_kernel(
    const float* __restrict__ X, u16* __restrict__ Hi, int total8, int pad8) {
    int i = blockIdx.x * 256 + threadIdx.x;
    if (i >= pad8) return;
    size_t base = (size_t)i * 8;
    if (i >= total8) {  // zero the pad rows (keeps MFMA tail clean)
        *(uint4*)(Hi + base) = make_uint4(0, 0, 0, 0);
        return;
    }
    float4 x0 = *(const float4*)(X + base);
    float4 x1 = *(const float4*)(X + base + 4);
    float xs[8] = {x0.x, x0.y, x0.z, x0.w, x1.x, x1.y, x1.z, x1.w};
    union { u16 s[8]; uint4 v; } h;
#pragma unroll
    for (int j = 0; j < 8; j++) h.s[j] = bf_hi(xs[j]);
    *(uint4*)(Hi + base) = h.v;
}

// --- transpose + split 4 weights: W[k][n] -> Wt[n][k] hi/lo -------------
// z=0..2: 512x512 (W_src,W_dst,W_skip); z=3: W_red 512x256.
__global__ __launch_bounds__(256) void split_wt_kernel(
    const float* __restrict__ Ws, const float* __restrict__ Wd,
    const float* __restrict__ Wk, const float* __restrict__ Wr,
    u16* __restrict__ Hi, u16* __restrict__ Lo) {
    __shared__ float t[32][33];
    int w = blockIdx.z;
    int ncols = (w == 3) ? 256 : 512;
    int n0 = blockIdx.y * 32;
    if (n0 >= ncols) return;
    const float* W = (w == 0) ? Ws : ((w == 1) ? Wd : ((w == 2) ? Wk : Wr));
    size_t obase = (size_t)w * 512 * 512;
    int k0 = blockIdx.x * 32;
    int tx = threadIdx.x, ty = threadIdx.y;  // 32 x 8
#pragma unroll
    for (int i = 0; i < 4; i++)
        t[ty * 4 + i][tx] = W[(size_t)(k0 + ty * 4 + i) * ncols + n0 + tx];
    __syncthreads();
#pragma unroll
    for (int i = 0; i < 4; i++) {
        float x = t[tx][ty * 4 + i];  // = W[k0+tx][n0+ty*4+i]
        u16 hh = bf_hi(x);
        size_t o = obase + (size_t)(n0 + ty * 4 + i) * 512 + k0 + tx;
        Hi[o] = hh;
        Lo[o] = bf_hi(x - bf_val(hh));
    }
}

// ------- fused triple MFMA GEMM v3: LDS double-buffer + XCD swizzle -----
// {fs,fd,skip} = feat @ {Ws,Wd,Wk}. A staged in LDS (2 buffers); loads for
// tile k+1 issued BEFORE the 16 MFMAs of tile k, LDS write (and its vmcnt
// wait) lands after the compute -> load latency overlaps MFMA. One barrier
// per k-tile. XCD swizzle (R8-proven: FETCH 127->29 MB) keeps A-tile HBM
// fetch at 1x and weights L2-resident.
__global__ __launch_bounds__(256) void gemm_mfma_triple(
    const u16* __restrict__ Fhi, const u16* __restrict__ Wthi,
    const float* __restrict__ b_src, const float* __restrict__ b_dst,
    const float* __restrict__ b_skip,
    u16* __restrict__ FS16, u16* __restrict__ FD16, float* __restrict__ h1) {
    __shared__ u16 As[2][128 * 40];
    int b = blockIdx.x;
    int xcd = b & 7, slot = b >> 3;
    int rt = (slot / 12) * 8 + xcd;
    if (rt >= N_RT) return;
    int cw = slot % 12;
    int w_idx = cw >> 2;
    int col0 = (cw & 3) * 128;
    int row0 = rt * 128;
    int tid = threadIdx.x;
    int lane = tid & 63, wave = tid >> 6;
    int wm = (wave & 1) * 64, wn = (wave >> 1) * 64;
    int quad = lane >> 4, l16 = lane & 15;

    // staging map: thread t -> row t>>1, 16-elem half (t&1)*16 (rows padded)
    int sr = tid >> 1, sh = (tid & 1) * 16;
    const u16* gA = Fhi + (size_t)(row0 + sr) * 512 + sh;
    int sOff = sr * 40 + sh;

    const u16* Wb = Wthi + (size_t)w_idx * 512 * 512;
    const u16* bP[4];
#pragma unroll
    for (int nt = 0; nt < 4; nt++)
        bP[nt] = Wb + (size_t)(col0 + wn + nt * 16 + l16) * 512 + quad * 8;

    floatx4 acc[4][4];
#pragma unroll
    for (int i = 0; i < 4; i++)
#pragma unroll
        for (int j = 0; j < 4; j++) acc[i][j] = (floatx4){0.f, 0.f, 0.f, 0.f};

    // prologue: tile 0
    uint4 ca0 = *(const uint4*)(gA);
    uint4 ca1 = *(const uint4*)(gA + 8);
    union { uint4 u; bf16x8 v; } bcur[4], bnxt[4];
#pragma unroll
    for (int nt = 0; nt < 4; nt++) bcur[nt].u = *(const uint4*)(bP[nt]);
    *(uint4*)(&As[0][sOff]) = ca0;
    *(uint4*)(&As[0][sOff + 8]) = ca1;
    __syncthreads();

    for (int kk = 0; kk < 16; kk++) {
        uint4 na0, na1;
        bool more = kk < 15;
        if (more) {
            int k1 = (kk + 1) * 32;
            na0 = *(const uint4*)(gA + k1);
            na1 = *(const uint4*)(gA + k1 + 8);
#pragma unroll
            for (int nt = 0; nt < 4; nt++) bnxt[nt].u = *(const uint4*)(bP[nt] + k1);
        }
        const u16* base = &As[kk & 1][0];
#pragma unroll
        for (int mt = 0; mt < 4; mt++) {
            bf16x8 ah = *(const bf16x8*)&base[(wm + mt * 16 + l16) * 40 + quad * 8];
#pragma unroll
            for (int nt = 0; nt < 4; nt++)
                acc[mt][nt] = __builtin_amdgcn_mfma_f32_16x16x32_bf16(ah, bcur[nt].v, acc[mt][nt], 0, 0, 0);
        }
        if (more) {
            u16* d = &As[(kk + 1) & 1][sOff];
            *(uint4*)(d) = na0;       // vmcnt wait lands HERE, after 16 MFMAs
            *(uint4*)(d + 8) = na1;
            __syncthreads();
#pragma unroll
            for (int nt = 0; nt < 4; nt++) bcur[nt] = bnxt[nt];
        }
    }

    const float* bias = (w_idx == 0) ? b_src : ((w_idx == 1) ? b_dst : b_skip);
    float bv[4];
#pragma unroll
    for (int nt = 0; nt < 4; nt++) bv[nt] = bias[col0 + wn + nt * 16 + l16];
#pragma unroll
    for (int mt = 0; mt < 4; mt++) {
#pragma unroll
        for (int r = 0; r < 4; r++) {
            int m = row0 + wm + mt * 16 + quad * 4 + r;
            if (m < N_NODES) {
#pragma unroll
                for (int nt = 0; nt < 4; nt++) {
                    int n = col0 + wn + nt * 16 + l16;
                    float vv = acc[mt][nt][r] + bv[nt];
                    if (w_idx == 0)      FS16[(size_t)m * 512 + n] = bf_hi(vv);
                    else if (w_idx == 1) FD16[(size_t)m * 512 + n] = bf_hi(vv);
                    else                 h1[(size_t)m * 512 + n] = vv;
                }
            }
        }
    }
}

// ------------------- MFMA GEMM (reducer): 3-term + BN fold --------------
__global__ __launch_bounds__(256) void gemm_mfma_red(
    const float* __restrict__ Af,
    const u16* __restrict__ Bhi, const u16* __restrict__ Blo,
    const float* __restrict__ bias, float* __restrict__ C,
    int Nrows, int M,
    const float* __restrict__ bscale, const float* __restrict__ bshift) {
    __shared__ u16 AsHi[128 * 40];
    __shared__ u16 AsLo[128 * 40];
    __shared__ float sBN[1024];
    int tid = threadIdx.x;
    int row0 = blockIdx.x * 128;
    int col0 = blockIdx.y * 128;
    int lane = tid & 63, wave = tid >> 6;
    int wm = (wave & 1) * 64, wn = (wave >> 1) * 64;
    int quad = lane >> 4, l16 = lane & 15;

    sBN[tid] = bscale[tid]; sBN[256 + tid] = bscale[256 + tid];
    sBN[512 + tid] = bshift[tid]; sBN[768 + tid] = bshift[256 + tid];
    __syncthreads();

    int sr = tid >> 1, sh = (tid & 1) * 16;
    int grow = row0 + sr;
    bool ok = grow < Nrows;
    u16* sA_hi = &AsHi[sr * 40 + sh];
    u16* sA_lo = &AsLo[sr * 40 + sh];

    floatx4 acc[4][4];
#pragma unroll
    for (int i = 0; i < 4; i++)
#pragma unroll
        for (int j = 0; j < 4; j++) acc[i][j] = (floatx4){0.f, 0.f, 0.f, 0.f};

    for (int k0 = 0; k0 < 512; k0 += 32) {
        float v[16];
        if (ok) {
            const float* g = Af + (size_t)grow * 512 + k0 + sh;
            *(float4*)&v[0]  = *(const float4*)(g);
            *(float4*)&v[4]  = *(const float4*)(g + 4);
            *(float4*)&v[8]  = *(const float4*)(g + 8);
            *(float4*)&v[12] = *(const float4*)(g + 12);
        } else {
#pragma unroll
            for (int j = 0; j < 16; j++) v[j] = 0.f;
        }
        union { u16 s[8]; uint4 u; } h0_, h1_, l0_, l1_;
#pragma unroll
        for (int j = 0; j < 16; j++) {
            int kc = k0 + sh + j;
            float x = v[j] * sBN[kc] + sBN[512 + kc];
            u16 hh = bf_hi(x);
            u16 ll = bf_hi(x - bf_val(hh));
            if (j < 8) { h0_.s[j] = hh; l0_.s[j] = ll; }
            else       { h1_.s[j - 8] = hh; l1_.s[j - 8] = ll; }
        }
        union { uint4 u; bf16x8 v; } bh[4], bl[4];
#pragma unroll
        for (int nt = 0; nt < 4; nt++) {
            size_t off = (size_t)(col0 + wn + nt * 16 + l16) * 512 + k0 + quad * 8;
            bh[nt].u = *(const uint4*)(Bhi + off);
            bl[nt].u = *(const uint4*)(Blo + off);
        }
        __syncthreads();
        *(uint4*)(sA_hi + 0) = h0_.u;
        *(uint4*)(sA_hi + 8) = h1_.u;
        *(uint4*)(sA_lo + 0) = l0_.u;
        *(uint4*)(sA_lo + 8) = l1_.u;
        __syncthreads();
#pragma unroll
        for (int mt = 0; mt < 4; mt++) {
            int me = (wm + mt * 16 + l16) * 40 + quad * 8;
            bf16x8 ah = *(const bf16x8*)&AsHi[me];
            bf16x8 al = *(const bf16x8*)&AsLo[me];
#pragma unroll
            for (int nt = 0; nt < 4; nt++) {
                acc[mt][nt] = __builtin_amdgcn_mfma_f32_16x16x32_bf16(ah, bh[nt].v, acc[mt][nt], 0, 0, 0);
                acc[mt][nt] = __builtin_amdgcn_mfma_f32_16x16x32_bf16(ah, bl[nt].v, acc[mt][nt], 0, 0, 0);
                acc[mt][nt] = __builtin_amdgcn_mfma_f32_16x16x32_bf16(al, bh[nt].v, acc[mt][nt], 0, 0, 0);
            }
        }
    }

    float bv[4];
#pragma unroll
    for (int nt = 0; nt < 4; nt++) bv[nt] = bias[col0 + wn + nt * 16 + l16];
#pragma unroll
    for (int mt = 0; mt < 4; mt++) {
#pragma unroll
        for (int r = 0; r < 4; r++) {
            int m = row0 + wm + mt * 16 + quad * 4 + r;
            if (m < Nrows) {
#pragma unroll
                for (int nt = 0; nt < 4; nt++) {
                    int n = col0 + wn + nt * 16 + l16;
                    C[(size_t)m * M + n] = acc[mt][nt][r] + bv[nt];
                }
            }
        }
    }
}

// ---------------- CSR build ----------------
__global__ void hist_kernel(const int* __restrict__ dst, int* __restrict__ counts) {
    int e = blockIdx.x * blockDim.x + threadIdx.x;
    if (e < N_EDGES) atomicAdd(&counts[dst[e]], 1);
}

__global__ __launch_bounds__(256) void scan_local_kernel(
    const int* __restrict__ counts, int* __restrict__ row_ptr, int* __restrict__ bsum) {
    __shared__ int buf[256];
    int b = blockIdx.x, tid = threadIdx.x;
    int i = b * 256 + tid;
    buf[tid] = (i < N_NODES) ? counts[i] : 0;
    __syncthreads();
    for (int off = 1; off < 256; off <<= 1) {
        int t = (tid >= off) ? buf[tid - off] : 0;
        __syncthreads();
        buf[tid] += t;
        __syncthreads();
    }
    if (i < N_NODES) row_ptr[i + 1] = buf[tid];
    if (tid == 255) bsum[b] = buf[255];
}

__global__ __launch_bounds__(256) void scan_fixup_kernel(
    const int* __restrict__ bsum, int* __restrict__ row_ptr) {
    __shared__ int red[256];
    int b = blockIdx.x, tid = threadIdx.x;
    red[tid] = (tid < b) ? bsum[tid] : 0;
    __syncthreads();
    for (int off = 128; off > 0; off >>= 1) {
        if (tid < off) red[tid] += red[tid + off];
        __syncthreads();
    }
    int offset = red[0];
    int i = b * 256 + tid;
    if (i < N_NODES) row_ptr[i + 1] += offset;
    if (b == 0 && tid == 0) row_ptr[0] = 0;
}

__global__ void scatter_kernel(const int* __restrict__ src, const int* __restrict__ dst,
                               const int* __restrict__ row_ptr,
                               int* __restrict__ cursor, int* __restrict__ csr_src) {
    int e = blockIdx.x * blockDim.x + threadIdx.x;
    if (e < N_EDGES) {
        int d = dst[e];
        int pos = atomicAdd(&cursor[d], 1);
        csr_src[row_ptr[d] + pos] = src[e];
    }
}

// -------- fused edge phase v4: SINGLE PASS ------------------------------
__global__ __launch_bounds__(256) void edge_fused_kernel(
    const u16* __restrict__ FS16, const u16* __restrict__ FD16,
    const float* __restrict__ attn, const int* __restrict__ csr_src,
    const int* __restrict__ row_ptr, float* __restrict__ h1) {
    __shared__ float red[3 * 512];
    __shared__ float den[2];
    int n = blockIdx.x, tid = threadIdx.x;
    int lane = tid & 63, wave = tid >> 6;
    int beg = row_ptr[n], end = row_ptr[n + 1], deg = end - beg;
    if (tid < 2) den[tid] = 0.f;

    float fdv[8], aw[8];
    {
        uint4 q = *(const uint4*)(FD16 + (size_t)n * 512 + 8 * lane);
        unpack2(q.x, fdv[0], fdv[1]); unpack2(q.y, fdv[2], fdv[3]);
        unpack2(q.z, fdv[4], fdv[5]); unpack2(q.w, fdv[6], fdv[7]);
        float4 a0 = *(const float4*)(attn + 8 * lane);
        float4 a1 = *(const float4*)(attn + 8 * lane + 4);
        aw[0] = a0.x; aw[1] = a0.y; aw[2] = a0.z; aw[3] = a0.w;
        aw[4] = a1.x; aw[5] = a1.y; aw[6] = a1.z; aw[7] = a1.w;
    }
    __syncthreads();  // den init visible before LDS atomics

    float acc[8] = {0.f, 0.f, 0.f, 0.f, 0.f, 0.f, 0.f, 0.f};
    float dp = 0.f;
    for (int j = wave; j < deg; j += 4) {
        int s = csr_src[beg + j];
        uint4 q = *(const uint4*)(FS16 + (size_t)s * 512 + 8 * lane);
        float f[8];
        unpack2(q.x, f[0], f[1]); unpack2(q.y, f[2], f[3]);
        unpack2(q.z, f[4], f[5]); unpack2(q.w, f[6], f[7]);
        float p = 0.f;
#pragma unroll
        for (int k = 0; k < 8; k++) p += lr(f[k] + fdv[k]) * aw[k];
#pragma unroll
        for (int off = 16; off > 0; off >>= 1) p += __shfl_xor(p, off, 64);
        float ex = expf(p);  // shift-invariant: no max pass needed
#pragma unroll
        for (int k = 0; k < 8; k++) acc[k] += ex * f[k];
        if ((lane & 31) == 0) dp += ex;
    }
    if ((lane & 31) == 0) atomicAdd(&den[lane >> 5], dp);

    if (wave > 0) {
        float* r = &red[(wave - 1) * 512 + lane * 8];
        *(float4*)(r + 0) = *(float4*)&acc[0];
        *(float4*)(r + 4) = *(float4*)&acc[4];
    }
    __syncthreads();
    if (wave == 0) {
#pragma unroll
        for (int w = 0; w < 3; w++) {
            const float* r = &red[w * 512 + lane * 8];
#pragma unroll
            for (int k = 0; k < 8; k++) acc[k] += r[k];
        }
        float d = (lane < 32) ? den[0] : den[1];
        float inv = d > 0.f ? 1.f / d : 0.f;
        float* hp = h1 + (size_t)n * 512 + 8 * lane;
        float4 s0 = *(float4*)(hp);
        float4 s1 = *(float4*)(hp + 4);
        float v[8];
#pragma unroll
        for (int k = 0; k < 8; k++) {
            float x = acc[k] * inv;
            v[k] = x > 0.f ? x : expm1f(x);
        }
        s0.x += v[0]; s0.y += v[1]; s0.z += v[2]; s0.w += v[3];
        s1.x += v[4]; s1.y += v[5]; s1.z += v[6]; s1.w += v[7];
        *(float4*)(hp) = s0;
        *(float4*)(hp + 4) = s1;
    }
}

// ---------------- BatchNorm stats ----------------
__global__ __launch_bounds__(256) void bn_stats_kernel(const float* __restrict__ h1,
                                                       float* __restrict__ stats,
                                                       int rows_per_block) {
    int tid = threadIdx.x;
    int r0 = blockIdx.x * rows_per_block;
    int r1 = min(r0 + rows_per_block, N_NODES);
    float s0 = 0.f, q0 = 0.f, s1 = 0.f, q1 = 0.f;
    for (int r = r0; r < r1; r++) {
        float a = h1[(size_t)r * F2 + tid];
        float b = h1[(size_t)r * F2 + 256 + tid];
        s0 += a; q0 += a * a;
        s1 += b; q1 += b * b;
    }
    atomicAdd(&stats[tid], s0);
    atomicAdd(&stats[256 + tid], s1);
    atomicAdd(&stats[512 + tid], q0);
    atomicAdd(&stats[512 + 256 + tid], q1);
}

__global__ void bn_finalize_kernel(const float* __restrict__ stats,
                                   const float* __restrict__ gamma,
                                   const float* __restrict__ beta,
                                   float* __restrict__ bscale, float* __restrict__ bshift) {
    int c = threadIdx.x;  // 512 threads
    float mu = stats[c] / (float)N_NODES;
    float var = stats[512 + c] / (float)N_NODES - mu * mu;
    float sc = gamma[c] * rsqrtf(var + EPS_BN);
    bscale[c] = sc;
    bshift[c] = beta[c] - mu * sc;
}

// ---------------- gate scores (b_gate dropped: softmax shift-invariant) -
__global__ __launch_bounds__(256) void gate_kernel(const float* __restrict__ hr,
                                                   const float* __restrict__ wg,
                                                   float* __restrict__ gate) {
    int n = blockIdx.x * 4 + (threadIdx.x >> 6);
    int lane = threadIdx.x & 63;
    const float4* row = (const float4*)(hr + (size_t)n * HID);
    const float4* w = (const float4*)wg;
    float4 a = row[lane], b = w[lane];
    float p = a.x * b.x + a.y * b.y + a.z * b.z + a.w * b.w;
#pragma unroll
    for (int off = 32; off > 0; off >>= 1) p += __shfl_down(p, off, 64);
    if (lane == 0) gate[n] = p;
}

// ---------------- per-graph attention pooling: 8 partial blocks / graph -
__device__ __forceinline__ int lower_bound_dev(const int* a, int n, int v) {
    int lo = 0, hi = n;
    while (lo < hi) {
        int mid = (lo + hi) >> 1;
        if (a[mid] < v) lo = mid + 1; else hi = mid;
    }
    return lo;
}

__global__ __launch_bounds__(256) void pool_partial_kernel(
    const float* __restrict__ hr, const float* __restrict__ gate,
    const int* __restrict__ gids, float* __restrict__ h_gnum,
    float* __restrict__ gden) {
    int b = blockIdx.x;
    int g = b >> 3, part = b & 7;
    int tid = threadIdx.x;
    int start = lower_bound_dev(gids, N_NODES, g);
    int end = lower_bound_dev(gids, N_NODES, g + 1);
    int span = end - start;
    int p_beg = start + (span * part) / 8;
    int p_end = start + (span * (part + 1)) / 8;
    if (p_beg >= p_end) return;
    __shared__ float wa[256];
    __shared__ float red[256];
    float acc = 0.f, denacc = 0.f;
    for (int cbeg = p_beg; cbeg < p_end; cbeg += 256) {
        int c = min(256, p_end - cbeg);
        float e = 0.f;
        if (tid < c) { e = expf(gate[cbeg + tid]); wa[tid] = e; }  // |gate| << 1: safe
        red[tid] = (tid < c) ? e : 0.f;
        __syncthreads();
        for (int off = 128; off > 0; off >>= 1) {
            if (tid < off) red[tid] += red[tid + off];
            __syncthreads();
        }
        denacc += red[0];
        for (int i = 0; i < c; i++) acc += wa[i] * hr[(size_t)(cbeg + i) * HID + tid];
        __syncthreads();
    }
    atomicAdd(&h_gnum[g * HID + tid], acc);
    if (tid == 0) atomicAdd(&gden[g], denacc);
}

// ---------------- classifier (finalizes pooling divide) -----------------
__global__ __launch_bounds__(128) void classifier_kernel(
    const float* __restrict__ h_gnum, const float* __restrict__ gden,
    const float* __restrict__ W1, const float* __restrict__ b1,
    const float* __restrict__ W2, const float* __restrict__ b2,
    float* __restrict__ out) {
    int g = blockIdx.x;
    int tid = threadIdx.x;  // 128
    __shared__ float hg[256];
    __shared__ float z1[128];
    float d = gden[g];
    float invd = d > 0.f ? 1.f / d : 0.f;
    hg[tid] = h_gnum[g * HID + tid] * invd;
    hg[tid + 128] = h_gnum[g * HID + tid + 128] * invd;
    __syncthreads();
    float a = b1[tid];
#pragma unroll 8
    for (int k = 0; k < 256; k++) a += hg[k] * W1[k * 128 + tid];
    z1[tid] = a > 0.f ? a : 0.f;
    __syncthreads();
    if (tid < 10) {
        float o = b2[tid];
#pragma unroll 8
        for (int j = 0; j < 128; j++) o += z1[j] * W2[j * 10 + tid];
        out[g * 10 + tid] = o;
    }
}

// ---------------- launcher ----------------
extern "C" void kernel_launch(void* const* d_in, const int* in_sizes, int n_in,
                              void* d_out, int out_size, void* d_ws, size_t ws_size,
                              hipStream_t stream) {
    const float* feat   = (const float*)d_in[0];
    const int*   src    = (const int*)d_in[1];
    const int*   dst    = (const int*)d_in[2];
    const int*   gids   = (const int*)d_in[3];
    const float* W_src  = (const float*)d_in[4];
    const float* b_src  = (const float*)d_in[5];
    const float* W_dst  = (const float*)d_in[6];
    const float* b_dst  = (const float*)d_in[7];
    const float* attn   = (const float*)d_in[8];
    const float* W_skip = (const float*)d_in[9];
    const float* b_skip = (const float*)d_in[10];
    const float* gamma  = (const float*)d_in[11];
    const float* beta   = (const float*)d_in[12];
    const float* W_red  = (const float*)d_in[13];
    const float* b_red  = (const float*)d_in[14];
    const float* w_gate = (const float*)d_in[15];
    const float* W1     = (const float*)d_in[17];
    const float* b1     = (const float*)d_in[18];
    const float* W2     = (const float*)d_in[19];
    const float* b2     = (const float*)d_in[20];
    float* out = (float*)d_out;

    char* p = (char*)d_ws;
    auto alloc = [&](size_t bytes) -> char* {
        char* r = p;
        p += (bytes + 255) & ~(size_t)255;
        return r;
    };
    u16*   FS16     = (u16*)alloc((size_t)N_NODES * F2 * 2);
    u16*   FD16     = (u16*)alloc((size_t)N_NODES * F2 * 2);
    float* h1       = (float*)alloc((size_t)N_NODES * F2 * 4);
    float* gate     = (float*)alloc((size_t)N_NODES * 4);
    float* stats    = (float*)alloc(1024 * 4);
    float* bn_scale = (float*)alloc(512 * 4);
    float* bn_shift = (float*)alloc(512 * 4);
    float* h_gnum   = (float*)alloc((size_t)N_GRAPH * HID * 4);
    float* gden     = (float*)alloc((size_t)N_GRAPH * 4);
    int* counts     = (int*)alloc((size_t)N_NODES * 4);
    int* row_ptr    = (int*)alloc((size_t)(N_NODES + 1) * 4);
    int* cursor     = (int*)alloc((size_t)N_NODES * 4);
    int* csr_src    = (int*)alloc((size_t)N_EDGES * 4);
    int* bsum       = (int*)alloc((size_t)SCAN_BLOCKS * 4);
    u16* Fhi        = (u16*)alloc((size_t)RT_PAD * IN_DIM * 2);  // padded; aliased as hr later
    u16* Wthi       = (u16*)alloc((size_t)4 * 512 * 512 * 2);
    u16* Wtlo       = (u16*)alloc((size_t)4 * 512 * 512 * 2);
    // hr (20.48 MB) aliases Fhi (20.58 MB): Fhi's last use (input GEMMs)
    // strictly precedes hr's first write (reducer GEMM).
    float* hr = (float*)Fhi;
    (void)ws_size; (void)in_sizes; (void)n_in; (void)out_size;

    const size_t WSZ = (size_t)512 * 512;

    // 1. init + input conversions
    init_zero_kernel<<<(N_NODES + 255) / 256, 256, 0, stream>>>(counts, cursor, stats, h_gnum, gden);
    split_feat_kernel<<<(RT_PAD * IN_DIM / 8 + 255) / 256, 256, 0, stream>>>(
        feat, Fhi, N_NODES * IN_DIM / 8, RT_PAD * IN_DIM / 8);
    split_wt_kernel<<<dim3(16, 16, 4), dim3(32, 8), 0, stream>>>(
        W_src, W_dst, W_skip, W_red, Wthi, Wtlo);

    // 2. fused input GEMM triple v3 (LDS dbuf pipeline + XCD swizzle)
    gemm_mfma_triple<<<dim3(((N_RT + 7) / 8) * 8 * 12), 256, 0, stream>>>(
        Fhi, Wthi, b_src, b_dst, b_skip, FS16, FD16, h1);

    // 3-5. CSR by dst
    hist_kernel<<<(N_EDGES + 255) / 256, 256, 0, stream>>>(dst, counts);
    scan_local_kernel<<<SCAN_BLOCKS, 256, 0, stream>>>(counts, row_ptr, bsum);
    scan_fixup_kernel<<<SCAN_BLOCKS, 256, 0, stream>>>(bsum, row_ptr);
    scatter_kernel<<<(N_EDGES + 255) / 256, 256, 0, stream>>>(src, dst, row_ptr, cursor, csr_src);

    // 6. fused edge phase v4 (single pass)
    edge_fused_kernel<<<N_NODES, 256, 0, stream>>>(FS16, FD16, attn, csr_src, row_ptr, h1);

    // 7-8. BatchNorm stats -> scale/shift
    bn_stats_kernel<<<500, 256, 0, stream>>>(h1, stats, 40);
    bn_finalize_kernel<<<1, 512, 0, stream>>>(stats, gamma, beta, bn_scale, bn_shift);

    // 9. hr = BN(h1) @ W_red + b_red  (MFMA, 3-term, BN fold at staging)
    dim3 g256((N_NODES + 127) / 128, 2);
    gemm_mfma_red<<<g256, 256, 0, stream>>>(
        h1, Wthi + 3 * WSZ, Wtlo + 3 * WSZ, b_red, hr, N_NODES, HID,
        bn_scale, bn_shift);

    // 10. gate
    gate_kernel<<<N_NODES / 4, 256, 0, stream>>>(hr, w_gate, gate);

    // 11. per-graph pooling (8 partial blocks per graph)
    pool_partial_kernel<<<N_GRAPH * 8, 256, 0, stream>>>(hr, gate, gids, h_gnum, gden);

    // 12. classifier (+ pooling divide)
    classifier_kernel<<<N_GRAPH, 128, 0, stream>>>(h_gnum, gden, W1, b1, W2, b2, out);
}

// Round 10
// 423.502 us; speedup vs baseline: 1.1279x; 1.0236x over previous
//
#include <hip/hip_runtime.h>
#include <math.h>

#define N_NODES 20000
#define N_EDGES 320000
#define N_GRAPH 64
#define IN_DIM  512
#define HID     256
#define F2      512   // HEADS*HID
#define EPS_BN  1e-5f
#define SLOPE   0.2f
#define SCAN_BLOCKS 79   // ceil(20000/256)
#define N_RT    157      // ceil(20000/128) row tiles
#define RT_PAD  20096    // 157*128: padded Fhi rows so tail A-loads are in-bounds

typedef unsigned short u16;
typedef __attribute__((ext_vector_type(8))) short bf16x8;
typedef __attribute__((ext_vector_type(4))) float floatx4;

// bf16 helpers: storage = upper 16 bits of fp32, round-to-nearest-even
__device__ __forceinline__ u16 bf_hi(float x) {
    unsigned int u = __float_as_uint(x);
    return (u16)((u + 0x7fffu + ((u >> 16) & 1u)) >> 16);
}
__device__ __forceinline__ float bf_val(u16 h) {
    return __uint_as_float((unsigned int)h << 16);
}
__device__ __forceinline__ void unpack2(unsigned int u, float& lo, float& hi) {
    lo = __uint_as_float(u << 16);
    hi = __uint_as_float(u & 0xffff0000u);
}
__device__ __forceinline__ float lr(float x) { return fmaxf(x, SLOPE * x); }

// ---------------- init: zero the ws regions that need it ----------------
__global__ void init_zero_kernel(int* counts, int* cursor, float* stats,
                                 float* h_gnum, float* gden) {
    int i = blockIdx.x * blockDim.x + threadIdx.x;
    if (i < N_NODES) { counts[i] = 0; cursor[i] = 0; }
    if (i < 1024) stats[i] = 0.f;
    if (i < N_GRAPH * HID) h_gnum[i] = 0.f;
    if (i < N_GRAPH) gden[i] = 0.f;
}

// ---------------- feat -> bf16 (row-major preserved, tail rows zeroed) --
__global__ __launch_bounds__(256) void split_feat_kernel(
    const float* __restrict__ X, u16* __restrict__ Hi, int total8, int pad8) {
    int i = blockIdx.x * 256 + threadIdx.x;
    if (i >= pad8) return;
    size_t base = (size_t)i * 8;
    if (i >= total8) {  // zero the pad rows (keeps MFMA tail clean)
        *(uint4*)(Hi + base) = make_uint4(0, 0, 0, 0);
        return;
    }
    float4 x0 = *(const float4*)(X + base);
    float4 x1 = *(const float4*)(X + base + 4);
    float xs[8] = {x0.x, x0.y, x0.z, x0.w, x1.x, x1.y, x1.z, x1.w};
    union { u16 s[8]; uint4 v; } h;
#pragma unroll
    for (int j = 0; j < 8; j++) h.s[j] = bf_hi(xs[j]);
    *(uint4*)(Hi + base) = h.v;
}

// --- transpose + split 4 weights: W[k][n] -> Wt[n][k] hi/lo -------------
// z=0..2: 512x512 (W_src,W_dst,W_skip); z=3: W_red 512x256.
__global__ __launch_bounds__(256) void split_wt_kernel(
    const float* __restrict__ Ws, const float* __restrict__ Wd,
    const float* __restrict__ Wk, const float* __restrict__ Wr,
    u16* __restrict__ Hi, u16* __restrict__ Lo) {
    __shared__ float t[32][33];
    int w = blockIdx.z;
    int ncols = (w == 3) ? 256 : 512;
    int n0 = blockIdx.y * 32;
    if (n0 >= ncols) return;
    const float* W = (w == 0) ? Ws : ((w == 1) ? Wd : ((w == 2) ? Wk : Wr));
    size_t obase = (size_t)w * 512 * 512;
    int k0 = blockIdx.x * 32;
    int tx = threadIdx.x, ty = threadIdx.y;  // 32 x 8
#pragma unroll
    for (int i = 0; i < 4; i++)
        t[ty * 4 + i][tx] = W[(size_t)(k0 + ty * 4 + i) * ncols + n0 + tx];
    __syncthreads();
#pragma unroll
    for (int i = 0; i < 4; i++) {
        float x = t[tx][ty * 4 + i];  // = W[k0+tx][n0+ty*4+i]
        u16 hh = bf_hi(x);
        size_t o = obase + (size_t)(n0 + ty * 4 + i) * 512 + k0 + tx;
        Hi[o] = hh;
        Lo[o] = bf_hi(x - bf_val(hh));
    }
}

// ------- fused triple MFMA GEMM v4: BK=64, 32 MFMAs/barrier -------------
// Cross-round evidence (R4 472 TF @48 MFMA/barrier vs R7/R9 295 TF @16):
// per-iteration latency is fixed; amortize it with more MFMA per sync.
// A staged in LDS (2 buffers, stride 72 = 2-way bank aliasing = free),
// loads for tile k+1 hoisted before the 32 MFMAs of tile k; B register-
// prefetched. XCD swizzle keeps FETCH at ~25 MB (R8/R9-proven).
__global__ __launch_bounds__(256) void gemm_mfma_triple(
    const u16* __restrict__ Fhi, const u16* __restrict__ Wthi,
    const float* __restrict__ b_src, const float* __restrict__ b_dst,
    const float* __restrict__ b_skip,
    u16* __restrict__ FS16, u16* __restrict__ FD16, float* __restrict__ h1) {
    __shared__ u16 As[2][128 * 72];
    int b = blockIdx.x;
    int xcd = b & 7, slot = b >> 3;
    int rt = (slot / 12) * 8 + xcd;
    if (rt >= N_RT) return;
    int cw = slot % 12;
    int w_idx = cw >> 2;
    int col0 = (cw & 3) * 128;
    int row0 = rt * 128;
    int tid = threadIdx.x;
    int lane = tid & 63, wave = tid >> 6;
    int wm = (wave & 1) * 64, wn = (wave >> 1) * 64;
    int quad = lane >> 4, l16 = lane & 15;

    // staging map: thread t -> row t>>1, 32-elem half (t&1)*32 (4x uint4)
    int sr = tid >> 1, sh = (tid & 1) * 32;
    const u16* gA = Fhi + (size_t)(row0 + sr) * 512 + sh;
    int sOff = sr * 72 + sh;

    const u16* Wb = Wthi + (size_t)w_idx * 512 * 512;
    const u16* bP[4];
#pragma unroll
    for (int nt = 0; nt < 4; nt++)
        bP[nt] = Wb + (size_t)(col0 + wn + nt * 16 + l16) * 512 + quad * 8;

    floatx4 acc[4][4];
#pragma unroll
    for (int i = 0; i < 4; i++)
#pragma unroll
        for (int j = 0; j < 4; j++) acc[i][j] = (floatx4){0.f, 0.f, 0.f, 0.f};

    // prologue: tile 0 (A -> LDS buf 0, B(0) -> bcur)
    union { uint4 u; bf16x8 v; } bcur[8], bnxt[8];
    {
        uint4 a0 = *(const uint4*)(gA + 0);
        uint4 a1 = *(const uint4*)(gA + 8);
        uint4 a2 = *(const uint4*)(gA + 16);
        uint4 a3 = *(const uint4*)(gA + 24);
#pragma unroll
        for (int nt = 0; nt < 4; nt++) {
            bcur[nt * 2 + 0].u = *(const uint4*)(bP[nt] + 0);
            bcur[nt * 2 + 1].u = *(const uint4*)(bP[nt] + 32);
        }
        *(uint4*)(&As[0][sOff + 0])  = a0;
        *(uint4*)(&As[0][sOff + 8])  = a1;
        *(uint4*)(&As[0][sOff + 16]) = a2;
        *(uint4*)(&As[0][sOff + 24]) = a3;
    }
    __syncthreads();

    for (int kk = 0; kk < 8; kk++) {
        uint4 na0, na1, na2, na3;
        bool more = kk < 7;
        if (more) {
            int k1 = (kk + 1) * 64;
            na0 = *(const uint4*)(gA + k1 + 0);
            na1 = *(const uint4*)(gA + k1 + 8);
            na2 = *(const uint4*)(gA + k1 + 16);
            na3 = *(const uint4*)(gA + k1 + 24);
#pragma unroll
            for (int nt = 0; nt < 4; nt++) {
                bnxt[nt * 2 + 0].u = *(const uint4*)(bP[nt] + k1 + 0);
                bnxt[nt * 2 + 1].u = *(const uint4*)(bP[nt] + k1 + 32);
            }
        }
        const u16* base = &As[kk & 1][0];
#pragma unroll
        for (int s = 0; s < 2; s++) {
#pragma unroll
            for (int mt = 0; mt < 4; mt++) {
                bf16x8 ah = *(const bf16x8*)&base[(wm + mt * 16 + l16) * 72 + s * 32 + quad * 8];
#pragma unroll
                for (int nt = 0; nt < 4; nt++)
                    acc[mt][nt] = __builtin_amdgcn_mfma_f32_16x16x32_bf16(ah, bcur[nt * 2 + s].v, acc[mt][nt], 0, 0, 0);
            }
        }
        if (more) {
            u16* d = &As[(kk + 1) & 1][sOff];
            *(uint4*)(d + 0)  = na0;   // vmcnt wait lands after the 32 MFMAs
            *(uint4*)(d + 8)  = na1;
            *(uint4*)(d + 16) = na2;
            *(uint4*)(d + 24) = na3;
            __syncthreads();
#pragma unroll
            for (int i = 0; i < 8; i++) bcur[i] = bnxt[i];
        }
    }

    const float* bias = (w_idx == 0) ? b_src : ((w_idx == 1) ? b_dst : b_skip);
    float bv[4];
#pragma unroll
    for (int nt = 0; nt < 4; nt++) bv[nt] = bias[col0 + wn + nt * 16 + l16];
#pragma unroll
    for (int mt = 0; mt < 4; mt++) {
#pragma unroll
        for (int r = 0; r < 4; r++) {
            int m = row0 + wm + mt * 16 + quad * 4 + r;
            if (m < N_NODES) {
#pragma unroll
                for (int nt = 0; nt < 4; nt++) {
                    int n = col0 + wn + nt * 16 + l16;
                    float vv = acc[mt][nt][r] + bv[nt];
                    if (w_idx == 0)      FS16[(size_t)m * 512 + n] = bf_hi(vv);
                    else if (w_idx == 1) FD16[(size_t)m * 512 + n] = bf_hi(vv);
                    else                 h1[(size_t)m * 512 + n] = vv;
                }
            }
        }
    }
}

// ------------------- MFMA GEMM (reducer): 3-term + BN fold --------------
__global__ __launch_bounds__(256) void gemm_mfma_red(
    const float* __restrict__ Af,
    const u16* __restrict__ Bhi, const u16* __restrict__ Blo,
    const float* __restrict__ bias, float* __restrict__ C,
    int Nrows, int M,
    const float* __restrict__ bscale, const float* __restrict__ bshift) {
    __shared__ u16 AsHi[128 * 40];
    __shared__ u16 AsLo[128 * 40];
    __shared__ float sBN[1024];
    int tid = threadIdx.x;
    int row0 = blockIdx.x * 128;
    int col0 = blockIdx.y * 128;
    int lane = tid & 63, wave = tid >> 6;
    int wm = (wave & 1) * 64, wn = (wave >> 1) * 64;
    int quad = lane >> 4, l16 = lane & 15;

    sBN[tid] = bscale[tid]; sBN[256 + tid] = bscale[256 + tid];
    sBN[512 + tid] = bshift[tid]; sBN[768 + tid] = bshift[256 + tid];
    __syncthreads();

    int sr = tid >> 1, sh = (tid & 1) * 16;
    int grow = row0 + sr;
    bool ok = grow < Nrows;
    u16* sA_hi = &AsHi[sr * 40 + sh];
    u16* sA_lo = &AsLo[sr * 40 + sh];

    floatx4 acc[4][4];
#pragma unroll
    for (int i = 0; i < 4; i++)
#pragma unroll
        for (int j = 0; j < 4; j++) acc[i][j] = (floatx4){0.f, 0.f, 0.f, 0.f};

    for (int k0 = 0; k0 < 512; k0 += 32) {
        float v[16];
        if (ok) {
            const float* g = Af + (size_t)grow * 512 + k0 + sh;
            *(float4*)&v[0]  = *(const float4*)(g);
            *(float4*)&v[4]  = *(const float4*)(g + 4);
            *(float4*)&v[8]  = *(const float4*)(g + 8);
            *(float4*)&v[12] = *(const float4*)(g + 12);
        } else {
#pragma unroll
            for (int j = 0; j < 16; j++) v[j] = 0.f;
        }
        union { u16 s[8]; uint4 u; } h0_, h1_, l0_, l1_;
#pragma unroll
        for (int j = 0; j < 16; j++) {
            int kc = k0 + sh + j;
            float x = v[j] * sBN[kc] + sBN[512 + kc];
            u16 hh = bf_hi(x);
            u16 ll = bf_hi(x - bf_val(hh));
            if (j < 8) { h0_.s[j] = hh; l0_.s[j] = ll; }
            else       { h1_.s[j - 8] = hh; l1_.s[j - 8] = ll; }
        }
        union { uint4 u; bf16x8 v; } bh[4], bl[4];
#pragma unroll
        for (int nt = 0; nt < 4; nt++) {
            size_t off = (size_t)(col0 + wn + nt * 16 + l16) * 512 + k0 + quad * 8;
            bh[nt].u = *(const uint4*)(Bhi + off);
            bl[nt].u = *(const uint4*)(Blo + off);
        }
        __syncthreads();
        *(uint4*)(sA_hi + 0) = h0_.u;
        *(uint4*)(sA_hi + 8) = h1_.u;
        *(uint4*)(sA_lo + 0) = l0_.u;
        *(uint4*)(sA_lo + 8) = l1_.u;
        __syncthreads();
#pragma unroll
        for (int mt = 0; mt < 4; mt++) {
            int me = (wm + mt * 16 + l16) * 40 + quad * 8;
            bf16x8 ah = *(const bf16x8*)&AsHi[me];
            bf16x8 al = *(const bf16x8*)&AsLo[me];
#pragma unroll
            for (int nt = 0; nt < 4; nt++) {
                acc[mt][nt] = __builtin_amdgcn_mfma_f32_16x16x32_bf16(ah, bh[nt].v, acc[mt][nt], 0, 0, 0);
                acc[mt][nt] = __builtin_amdgcn_mfma_f32_16x16x32_bf16(ah, bl[nt].v, acc[mt][nt], 0, 0, 0);
                acc[mt][nt] = __builtin_amdgcn_mfma_f32_16x16x32_bf16(al, bh[nt].v, acc[mt][nt], 0, 0, 0);
            }
        }
    }

    float bv[4];
#pragma unroll
    for (int nt = 0; nt < 4; nt++) bv[nt] = bias[col0 + wn + nt * 16 + l16];
#pragma unroll
    for (int mt = 0; mt < 4; mt++) {
#pragma unroll
        for (int r = 0; r < 4; r++) {
            int m = row0 + wm + mt * 16 + quad * 4 + r;
            if (m < Nrows) {
#pragma unroll
                for (int nt = 0; nt < 4; nt++) {
                    int n = col0 + wn + nt * 16 + l16;
                    C[(size_t)m * M + n] = acc[mt][nt][r] + bv[nt];
                }
            }
        }
    }
}

// ---------------- CSR build ----------------
__global__ void hist_kernel(const int* __restrict__ dst, int* __restrict__ counts) {
    int e = blockIdx.x * blockDim.x + threadIdx.x;
    if (e < N_EDGES) atomicAdd(&counts[dst[e]], 1);
}

__global__ __launch_bounds__(256) void scan_local_kernel(
    const int* __restrict__ counts, int* __restrict__ row_ptr, int* __restrict__ bsum) {
    __shared__ int buf[256];
    int b = blockIdx.x, tid = threadIdx.x;
    int i = b * 256 + tid;
    buf[tid] = (i < N_NODES) ? counts[i] : 0;
    __syncthreads();
    for (int off = 1; off < 256; off <<= 1) {
        int t = (tid >= off) ? buf[tid - off] : 0;
        __syncthreads();
        buf[tid] += t;
        __syncthreads();
    }
    if (i < N_NODES) row_ptr[i + 1] = buf[tid];
    if (tid == 255) bsum[b] = buf[255];
}

__global__ __launch_bounds__(256) void scan_fixup_kernel(
    const int* __restrict__ bsum, int* __restrict__ row_ptr) {
    __shared__ int red[256];
    int b = blockIdx.x, tid = threadIdx.x;
    red[tid] = (tid < b) ? bsum[tid] : 0;
    __syncthreads();
    for (int off = 128; off > 0; off >>= 1) {
        if (tid < off) red[tid] += red[tid + off];
        __syncthreads();
    }
    int offset = red[0];
    int i = b * 256 + tid;
    if (i < N_NODES) row_ptr[i + 1] += offset;
    if (b == 0 && tid == 0) row_ptr[0] = 0;
}

__global__ void scatter_kernel(const int* __restrict__ src, const int* __restrict__ dst,
                               const int* __restrict__ row_ptr,
                               int* __restrict__ cursor, int* __restrict__ csr_src) {
    int e = blockIdx.x * blockDim.x + threadIdx.x;
    if (e < N_EDGES) {
        int d = dst[e];
        int pos = atomicAdd(&cursor[d], 1);
        csr_src[row_ptr[d] + pos] = src[e];
    }
}

// -------- fused edge phase v4: SINGLE PASS ------------------------------
__global__ __launch_bounds__(256) void edge_fused_kernel(
    const u16* __restrict__ FS16, const u16* __restrict__ FD16,
    const float* __restrict__ attn, const int* __restrict__ csr_src,
    const int* __restrict__ row_ptr, float* __restrict__ h1) {
    __shared__ float red[3 * 512];
    __shared__ float den[2];
    int n = blockIdx.x, tid = threadIdx.x;
    int lane = tid & 63, wave = tid >> 6;
    int beg = row_ptr[n], end = row_ptr[n + 1], deg = end - beg;
    if (tid < 2) den[tid] = 0.f;

    float fdv[8], aw[8];
    {
        uint4 q = *(const uint4*)(FD16 + (size_t)n * 512 + 8 * lane);
        unpack2(q.x, fdv[0], fdv[1]); unpack2(q.y, fdv[2], fdv[3]);
        unpack2(q.z, fdv[4], fdv[5]); unpack2(q.w, fdv[6], fdv[7]);
        float4 a0 = *(const float4*)(attn + 8 * lane);
        float4 a1 = *(const float4*)(attn + 8 * lane + 4);
        aw[0] = a0.x; aw[1] = a0.y; aw[2] = a0.z; aw[3] = a0.w;
        aw[4] = a1.x; aw[5] = a1.y; aw[6] = a1.z; aw[7] = a1.w;
    }
    __syncthreads();  // den init visible before LDS atomics

    float acc[8] = {0.f, 0.f, 0.f, 0.f, 0.f, 0.f, 0.f, 0.f};
    float dp = 0.f;
    for (int j = wave; j < deg; j += 4) {
        int s = csr_src[beg + j];
        uint4 q = *(const uint4*)(FS16 + (size_t)s * 512 + 8 * lane);
        float f[8];
        unpack2(q.x, f[0], f[1]); unpack2(q.y, f[2], f[3]);
        unpack2(q.z, f[4], f[5]); unpack2(q.w, f[6], f[7]);
        float p = 0.f;
#pragma unroll
        for (int k = 0; k < 8; k++) p += lr(f[k] + fdv[k]) * aw[k];
#pragma unroll
        for (int off = 16; off > 0; off >>= 1) p += __shfl_xor(p, off, 64);
        float ex = expf(p);  // shift-invariant: no max pass needed
#pragma unroll
        for (int k = 0; k < 8; k++) acc[k] += ex * f[k];
        if ((lane & 31) == 0) dp += ex;
    }
    if ((lane & 31) == 0) atomicAdd(&den[lane >> 5], dp);

    if (wave > 0) {
        float* r = &red[(wave - 1) * 512 + lane * 8];
        *(float4*)(r + 0) = *(float4*)&acc[0];
        *(float4*)(r + 4) = *(float4*)&acc[4];
    }
    __syncthreads();
    if (wave == 0) {
#pragma unroll
        for (int w = 0; w < 3; w++) {
            const float* r = &red[w * 512 + lane * 8];
#pragma unroll
            for (int k = 0; k < 8; k++) acc[k] += r[k];
        }
        float d = (lane < 32) ? den[0] : den[1];
        float inv = d > 0.f ? 1.f / d : 0.f;
        float* hp = h1 + (size_t)n * 512 + 8 * lane;
        float4 s0 = *(float4*)(hp);
        float4 s1 = *(float4*)(hp + 4);
        float v[8];
#pragma unroll
        for (int k = 0; k < 8; k++) {
            float x = acc[k] * inv;
            v[k] = x > 0.f ? x : expm1f(x);
        }
        s0.x += v[0]; s0.y += v[1]; s0.z += v[2]; s0.w += v[3];
        s1.x += v[4]; s1.y += v[5]; s1.z += v[6]; s1.w += v[7];
        *(float4*)(hp) = s0;
        *(float4*)(hp + 4) = s1;
    }
}

// ---------------- BatchNorm stats ----------------
__global__ __launch_bounds__(256) void bn_stats_kernel(const float* __restrict__ h1,
                                                       float* __restrict__ stats,
                                                       int rows_per_block) {
    int tid = threadIdx.x;
    int r0 = blockIdx.x * rows_per_block;
    int r1 = min(r0 + rows_per_block, N_NODES);
    float s0 = 0.f, q0 = 0.f, s1 = 0.f, q1 = 0.f;
    for (int r = r0; r < r1; r++) {
        float a = h1[(size_t)r * F2 + tid];
        float b = h1[(size_t)r * F2 + 256 + tid];
        s0 += a; q0 += a * a;
        s1 += b; q1 += b * b;
    }
    atomicAdd(&stats[tid], s0);
    atomicAdd(&stats[256 + tid], s1);
    atomicAdd(&stats[512 + tid], q0);
    atomicAdd(&stats[512 + 256 + tid], q1);
}

__global__ void bn_finalize_kernel(const float* __restrict__ stats,
                                   const float* __restrict__ gamma,
                                   const float* __restrict__ beta,
                                   float* __restrict__ bscale, float* __restrict__ bshift) {
    int c = threadIdx.x;  // 512 threads
    float mu = stats[c] / (float)N_NODES;
    float var = stats[512 + c] / (float)N_NODES - mu * mu;
    float sc = gamma[c] * rsqrtf(var + EPS_BN);
    bscale[c] = sc;
    bshift[c] = beta[c] - mu * sc;
}

// ---------------- gate scores (b_gate dropped: softmax shift-invariant) -
__global__ __launch_bounds__(256) void gate_kernel(const float* __restrict__ hr,
                                                   const float* __restrict__ wg,
                                                   float* __restrict__ gate) {
    int n = blockIdx.x * 4 + (threadIdx.x >> 6);
    int lane = threadIdx.x & 63;
    const float4* row = (const float4*)(hr + (size_t)n * HID);
    const float4* w = (const float4*)wg;
    float4 a = row[lane], b = w[lane];
    float p = a.x * b.x + a.y * b.y + a.z * b.z + a.w * b.w;
#pragma unroll
    for (int off = 32; off > 0; off >>= 1) p += __shfl_down(p, off, 64);
    if (lane == 0) gate[n] = p;
}

// ---------------- per-graph attention pooling: 8 partial blocks / graph -
__device__ __forceinline__ int lower_bound_dev(const int* a, int n, int v) {
    int lo = 0, hi = n;
    while (lo < hi) {
        int mid = (lo + hi) >> 1;
        if (a[mid] < v) lo = mid + 1; else hi = mid;
    }
    return lo;
}

__global__ __launch_bounds__(256) void pool_partial_kernel(
    const float* __restrict__ hr, const float* __restrict__ gate,
    const int* __restrict__ gids, float* __restrict__ h_gnum,
    float* __restrict__ gden) {
    int b = blockIdx.x;
    int g = b >> 3, part = b & 7;
    int tid = threadIdx.x;
    int start = lower_bound_dev(gids, N_NODES, g);
    int end = lower_bound_dev(gids, N_NODES, g + 1);
    int span = end - start;
    int p_beg = start + (span * part) / 8;
    int p_end = start + (span * (part + 1)) / 8;
    if (p_beg >= p_end) return;
    __shared__ float wa[256];
    __shared__ float red[256];
    float acc = 0.f, denacc = 0.f;
    for (int cbeg = p_beg; cbeg < p_end; cbeg += 256) {
        int c = min(256, p_end - cbeg);
        float e = 0.f;
        if (tid < c) { e = expf(gate[cbeg + tid]); wa[tid] = e; }  // |gate| << 1: safe
        red[tid] = (tid < c) ? e : 0.f;
        __syncthreads();
        for (int off = 128; off > 0; off >>= 1) {
            if (tid < off) red[tid] += red[tid + off];
            __syncthreads();
        }
        denacc += red[0];
        for (int i = 0; i < c; i++) acc += wa[i] * hr[(size_t)(cbeg + i) * HID + tid];
        __syncthreads();
    }
    atomicAdd(&h_gnum[g * HID + tid], acc);
    if (tid == 0) atomicAdd(&gden[g], denacc);
}

// ---------------- classifier (finalizes pooling divide) -----------------
__global__ __launch_bounds__(128) void classifier_kernel(
    const float* __restrict__ h_gnum, const float* __restrict__ gden,
    const float* __restrict__ W1, const float* __restrict__ b1,
    const float* __restrict__ W2, const float* __restrict__ b2,
    float* __restrict__ out) {
    int g = blockIdx.x;
    int tid = threadIdx.x;  // 128
    __shared__ float hg[256];
    __shared__ float z1[128];
    float d = gden[g];
    float invd = d > 0.f ? 1.f / d : 0.f;
    hg[tid] = h_gnum[g * HID + tid] * invd;
    hg[tid + 128] = h_gnum[g * HID + tid + 128] * invd;
    __syncthreads();
    float a = b1[tid];
#pragma unroll 8
    for (int k = 0; k < 256; k++) a += hg[k] * W1[k * 128 + tid];
    z1[tid] = a > 0.f ? a : 0.f;
    __syncthreads();
    if (tid < 10) {
        float o = b2[tid];
#pragma unroll 8
        for (int j = 0; j < 128; j++) o += z1[j] * W2[j * 10 + tid];
        out[g * 10 + tid] = o;
    }
}

// ---------------- launcher ----------------
extern "C" void kernel_launch(void* const* d_in, const int* in_sizes, int n_in,
                              void* d_out, int out_size, void* d_ws, size_t ws_size,
                              hipStream_t stream) {
    const float* feat   = (const float*)d_in[0];
    const int*   src    = (const int*)d_in[1];
    const int*   dst    = (const int*)d_in[2];
    const int*   gids   = (const int*)d_in[3];
    const float* W_src  = (const float*)d_in[4];
    const float* b_src  = (const float*)d_in[5];
    const float* W_dst  = (const float*)d_in[6];
    const float* b_dst  = (const float*)d_in[7];
    const float* attn   = (const float*)d_in[8];
    const float* W_skip = (const float*)d_in[9];
    const float* b_skip = (const float*)d_in[10];
    const float* gamma  = (const float*)d_in[11];
    const float* beta   = (const float*)d_in[12];
    const float* W_red  = (const float*)d_in[13];
    const float* b_red  = (const float*)d_in[14];
    const float* w_gate = (const float*)d_in[15];
    const float* W1     = (const float*)d_in[17];
    const float* b1     = (const float*)d_in[18];
    const float* W2     = (const float*)d_in[19];
    const float* b2     = (const float*)d_in[20];
    float* out = (float*)d_out;

    char* p = (char*)d_ws;
    auto alloc = [&](size_t bytes) -> char* {
        char* r = p;
        p += (bytes + 255) & ~(size_t)255;
        return r;
    };
    u16*   FS16     = (u16*)alloc((size_t)N_NODES * F2 * 2);
    u16*   FD16     = (u16*)alloc((size_t)N_NODES * F2 * 2);
    float* h1       = (float*)alloc((size_t)N_NODES * F2 * 4);
    float* gate     = (float*)alloc((size_t)N_NODES * 4);
    float* stats    = (float*)alloc(1024 * 4);
    float* bn_scale = (float*)alloc(512 * 4);
    float* bn_shift = (float*)alloc(512 * 4);
    float* h_gnum   = (float*)alloc((size_t)N_GRAPH * HID * 4);
    float* gden     = (float*)alloc((size_t)N_GRAPH * 4);
    int* counts     = (int*)alloc((size_t)N_NODES * 4);
    int* row_ptr    = (int*)alloc((size_t)(N_NODES + 1) * 4);
    int* cursor     = (int*)alloc((size_t)N_NODES * 4);
    int* csr_src    = (int*)alloc((size_t)N_EDGES * 4);
    int* bsum       = (int*)alloc((size_t)SCAN_BLOCKS * 4);
    u16* Fhi        = (u16*)alloc((size_t)RT_PAD * IN_DIM * 2);  // padded; aliased as hr later
    u16* Wthi       = (u16*)alloc((size_t)4 * 512 * 512 * 2);
    u16* Wtlo       = (u16*)alloc((size_t)4 * 512 * 512 * 2);
    // hr (20.48 MB) aliases Fhi (20.58 MB): Fhi's last use (input GEMMs)
    // strictly precedes hr's first write (reducer GEMM).
    float* hr = (float*)Fhi;
    (void)ws_size; (void)in_sizes; (void)n_in; (void)out_size;

    const size_t WSZ = (size_t)512 * 512;

    // 1. init + input conversions
    init_zero_kernel<<<(N_NODES + 255) / 256, 256, 0, stream>>>(counts, cursor, stats, h_gnum, gden);
    split_feat_kernel<<<(RT_PAD * IN_DIM / 8 + 255) / 256, 256, 0, stream>>>(
        feat, Fhi, N_NODES * IN_DIM / 8, RT_PAD * IN_DIM / 8);
    split_wt_kernel<<<dim3(16, 16, 4), dim3(32, 8), 0, stream>>>(
        W_src, W_dst, W_skip, W_red, Wthi, Wtlo);

    // 2. fused input GEMM triple v4 (BK=64, 32 MFMAs/barrier, XCD swizzle)
    gemm_mfma_triple<<<dim3(((N_RT + 7) / 8) * 8 * 12), 256, 0, stream>>>(
        Fhi, Wthi, b_src, b_dst, b_skip, FS16, FD16, h1);

    // 3-5. CSR by dst
    hist_kernel<<<(N_EDGES + 255) / 256, 256, 0, stream>>>(dst, counts);
    scan_local_kernel<<<SCAN_BLOCKS, 256, 0, stream>>>(counts, row_ptr, bsum);
    scan_fixup_kernel<<<SCAN_BLOCKS, 256, 0, stream>>>(bsum, row_ptr);
    scatter_kernel<<<(N_EDGES + 255) / 256, 256, 0, stream>>>(src, dst, row_ptr, cursor, csr_src);

    // 6. fused edge phase v4 (single pass)
    edge_fused_kernel<<<N_NODES, 256, 0, stream>>>(FS16, FD16, attn, csr_src, row_ptr, h1);

    // 7-8. BatchNorm stats -> scale/shift
    bn_stats_kernel<<<500, 256, 0, stream>>>(h1, stats, 40);
    bn_finalize_kernel<<<1, 512, 0, stream>>>(stats, gamma, beta, bn_scale, bn_shift);

    // 9. hr = BN(h1) @ W_red + b_red  (MFMA, 3-term, BN fold at staging)
    dim3 g256((N_NODES + 127) / 128, 2);
    gemm_mfma_red<<<g256, 256, 0, stream>>>(
        h1, Wthi + 3 * WSZ, Wtlo + 3 * WSZ, b_red, hr, N_NODES, HID,
        bn_scale, bn_shift);

    // 10. gate
    gate_kernel<<<N_NODES / 4, 256, 0, stream>>>(hr, w_gate, gate);

    // 11. per-graph pooling (8 partial blocks per graph)
    pool_partial_kernel<<<N_GRAPH * 8, 256, 0, stream>>>(hr, gate, gids, h_gnum, gden);

    // 12. classifier (+ pooling divide)
    classifier_kernel<<<N_GRAPH, 128, 0, stream>>>(h_gnum, gden, W1, b1, W2, b2, out);
}